// Round 1
// baseline (1786.244 us; speedup 1.0000x reference)
//
#include <hip/hip_runtime.h>
#include <hip/hip_bf16.h>
#include <math.h>

#define N_ 40000
#define E_ 640000

__device__ __forceinline__ float rdlane(float v, int l) {
    return __int_as_float(__builtin_amdgcn_readlane(__float_as_int(v), l));
}

// ---------------- CSR build ----------------
__global__ void k_count(const int* __restrict__ dst, int* __restrict__ counts) {
    for (int e = blockIdx.x * blockDim.x + threadIdx.x; e < E_; e += gridDim.x * blockDim.x)
        atomicAdd(&counts[dst[e]], 1);
}

__global__ void k_scan(const int* __restrict__ counts, int* __restrict__ rowptr,
                       int* __restrict__ cursor) {
    __shared__ int buf[1024];
    int t = threadIdx.x;
    int carry = 0;
    for (int base = 0; base < N_; base += 1024) {
        int i = base + t;
        int v = (i < N_) ? counts[i] : 0;
        buf[t] = v;
        __syncthreads();
        for (int off = 1; off < 1024; off <<= 1) {
            int add = (t >= off) ? buf[t - off] : 0;
            __syncthreads();
            buf[t] += add;
            __syncthreads();
        }
        int incl = buf[t];
        int excl = incl - v;
        if (i < N_) { rowptr[i] = carry + excl; cursor[i] = carry + excl; }
        int total = buf[1023];
        __syncthreads();
        carry += total;
    }
    if (t == 0) rowptr[N_] = carry;
}

__global__ void k_fill(const int* __restrict__ src, const int* __restrict__ dst,
                       int* __restrict__ cursor, int* __restrict__ srcv) {
    for (int e = blockIdx.x * blockDim.x + threadIdx.x; e < E_; e += gridDim.x * blockDim.x) {
        int d = dst[e];
        int pos = atomicAdd(&cursor[d], 1);
        srcv[pos] = src[e];
    }
}

// ---------------- GEMM [N,128] x [128,128] (+bias) ----------------
__global__ __launch_bounds__(256) void k_gemm128(const float* __restrict__ A,
                                                 const float* __restrict__ W,
                                                 const float* __restrict__ bias,
                                                 float* __restrict__ C) {
    __shared__ float As[8 * 128];
    int t = threadIdx.x;
    int r0 = blockIdx.x * 8;
    *(float4*)(As + t * 4) = *(const float4*)(A + (size_t)r0 * 128 + t * 4);
    __syncthreads();
    int c = t & 127, g = t >> 7;
    float a0 = 0.f, a1 = 0.f, a2 = 0.f, a3 = 0.f;
#pragma unroll 4
    for (int k = 0; k < 128; k++) {
        float wv = W[k * 128 + c];
        a0 += As[(g * 4 + 0) * 128 + k] * wv;
        a1 += As[(g * 4 + 1) * 128 + k] * wv;
        a2 += As[(g * 4 + 2) * 128 + k] * wv;
        a3 += As[(g * 4 + 3) * 128 + k] * wv;
    }
    float bv = bias ? bias[c] : 0.f;
    C[(size_t)(r0 + g * 4 + 0) * 128 + c] = a0 + bv;
    C[(size_t)(r0 + g * 4 + 1) * 128 + c] = a1 + bv;
    C[(size_t)(r0 + g * 4 + 2) * 128 + c] = a2 + bv;
    C[(size_t)(r0 + g * 4 + 3) * 128 + c] = a3 + bv;
}

// ---------------- per-node attention logits el/er ----------------
template <int H>
__global__ __launch_bounds__(256) void k_elr(const float* __restrict__ feat,
                                             const float* __restrict__ al,
                                             const float* __restrict__ ar,
                                             float* __restrict__ el, float* __restrict__ er) {
    int lane = threadIdx.x & 63;
    int n = blockIdx.x * 4 + (threadIdx.x >> 6);
    if (n >= N_) return;
    float2 f = *(const float2*)(feat + (size_t)n * 128 + 2 * lane);
    float2 a = *(const float2*)(al + 2 * lane);
    float2 b = *(const float2*)(ar + 2 * lane);
    float pl = f.x * a.x + f.y * a.y;
    float pr = f.x * b.x + f.y * b.y;
    constexpr int G = 64 / H;  // lanes per head group
#pragma unroll
    for (int off = 1; off < G; off <<= 1) {
        pl += __shfl_xor(pl, off);
        pr += __shfl_xor(pr, off);
    }
    if ((lane & (G - 1)) == 0) {
        int hh = lane / G;
        el[(size_t)n * H + hh] = pl;
        er[(size_t)n * H + hh] = pr;
    }
}

// ---------------- GAT edge-softmax + aggregate (wave per dst node) ----------------
template <int H>
__global__ __launch_bounds__(256) void k_gat_agg(const float* __restrict__ feat,
                                                 const float* __restrict__ el,
                                                 const float* __restrict__ er,
                                                 const int* __restrict__ rowptr,
                                                 const int* __restrict__ srcv,
                                                 const float* __restrict__ bias,
                                                 float* __restrict__ xout) {
    int lane = threadIdx.x & 63;
    int n = blockIdx.x * 4 + (threadIdx.x >> 6);
    if (n >= N_) return;
    int beg = rowptr[n], end = rowptr[n + 1];
    int f0 = 2 * lane;
    if (beg == end) {
        *(float2*)(xout + (size_t)n * 128 + f0) = *(const float2*)(bias + f0);
        return;
    }
    constexpr int LH = (H == 8) ? 3 : 0;
    int h = lane & (H - 1);
    float ern = er[(size_t)n * H + h];
    float m = -INFINITY, ss = 0.f;
    for (int e = beg + (lane >> LH); e < end; e += (64 >> LH)) {
        int sI = srcv[e];
        float x = el[(size_t)sI * H + h] + ern;
        float lr = x > 0.f ? x : 0.2f * x;
        if (lr > m) { ss = ss * __expf(m - lr) + 1.f; m = lr; }
        else ss += __expf(lr - m);
    }
#pragma unroll
    for (int off = H; off < 64; off <<= 1) {
        float om = __shfl_xor(m, off);
        float os = __shfl_xor(ss, off);
        float nm = fmaxf(m, om);
        float p1 = (m == -INFINITY) ? 0.f : ss * __expf(m - nm);
        float p2 = (om == -INFINITY) ? 0.f : os * __expf(om - nm);
        m = nm; ss = p1 + p2;
    }
    int hf = (lane * H) >> 6;  // head owning feature f0
    float mh = __shfl(m, hf);
    float dh = __shfl(ss, hf);
    float inv_d = 1.f / dh;
    float ernf = er[(size_t)n * H + hf];
    float accx = 0.f, accy = 0.f;
    for (int e = beg; e < end; ++e) {
        int sI = srcv[e];
        float x = el[(size_t)sI * H + hf] + ernf;
        float lr = x > 0.f ? x : 0.2f * x;
        float a = __expf(lr - mh) * inv_d;
        float2 f2 = *(const float2*)(feat + (size_t)sI * 128 + f0);
        accx += a * f2.x;
        accy += a * f2.y;
    }
    float2 b2 = *(const float2*)(bias + f0);
    *(float2*)(xout + (size_t)n * 128 + f0) = make_float2(accx + b2.x, accy + b2.y);
}

// ---------------- BN stats ----------------
__global__ __launch_bounds__(256) void k_bn_stats(const float* __restrict__ x,
                                                  float* __restrict__ sum,
                                                  float* __restrict__ sumsq) {
    __shared__ float ls[256], lq[256];
    int t = threadIdx.x;
    int col = t & 127, half = t >> 7;
    float s = 0.f, q = 0.f;
    for (int r = blockIdx.x * 2 + half; r < N_; r += gridDim.x * 2) {
        float v = x[(size_t)r * 128 + col];
        s += v; q += v * v;
    }
    ls[t] = s; lq[t] = q;
    __syncthreads();
    if (t < 128) {
        atomicAdd(&sum[col], ls[t] + ls[t + 128]);
        atomicAdd(&sumsq[col], lq[t] + lq[t + 128]);
    }
}

// ---------------- BN apply + ELU + residual (+mask) ----------------
__global__ __launch_bounds__(256) void k_bn_apply(const float* __restrict__ x,
                                                  const float* __restrict__ hprev,
                                                  const float* __restrict__ sum,
                                                  const float* __restrict__ sumsq,
                                                  const float* __restrict__ g,
                                                  const float* __restrict__ b,
                                                  float* __restrict__ out, int do_mask) {
    int i = blockIdx.x * blockDim.x + threadIdx.x;
    if (i >= N_ * 128) return;
    int c = i & 127;
    const float invN = 1.f / (float)N_;
    float mu = sum[c] * invN;
    float var = sumsq[c] * invN - mu * mu;
    float inv = rsqrtf(var + 1e-5f);
    float y = g[c] * (x[i] - mu) * inv + b[c];
    y = y > 0.f ? y : (__expf(y) - 1.f);
    float hv = hprev[i] + y;
    if (do_mask && isinf(hv)) hv = 1e9f;
    out[i] = hv;
}

// ---------------- assignment softmax s = softmax(h@Wa+ba) ----------------
__global__ __launch_bounds__(128) void k_s(const float* __restrict__ h,
                                           const float* __restrict__ Wa,
                                           const float* __restrict__ ba,
                                           float* __restrict__ s) {
    __shared__ float hrow[128];
    __shared__ float red[128];
    int n = blockIdx.x, t = threadIdx.x;
    hrow[t] = h[(size_t)n * 128 + t];
    __syncthreads();
    float acc = 0.f;
    if (t < 100) {
        acc = ba[t];
        for (int k = 0; k < 128; k++) acc += hrow[k] * Wa[k * 100 + t];
    }
    red[t] = (t < 100) ? acc : -INFINITY;
    __syncthreads();
    for (int off = 64; off > 0; off >>= 1) {
        if (t < off) red[t] = fmaxf(red[t], red[t + off]);
        __syncthreads();
    }
    float mx = red[0];
    __syncthreads();
    float ex = (t < 100) ? __expf(acc - mx) : 0.f;
    red[t] = ex;
    __syncthreads();
    for (int off = 64; off > 0; off >>= 1) {
        if (t < off) red[t] += red[t + off];
        __syncthreads();
    }
    float den = red[0];
    if (t < 100) s[(size_t)n * 100 + t] = ex / den;
}

// ---------------- h_coarse = s^T @ h_fine ----------------
__global__ __launch_bounds__(256) void k_coarse(const float* __restrict__ s,
                                                const float* __restrict__ hf,
                                                float* __restrict__ hc) {
    __shared__ float ssh[100];
    __shared__ float hsh[128];
    int t = threadIdx.x;
    int col = t & 127, half = t >> 7;
    float acc[50];
#pragma unroll
    for (int i = 0; i < 50; i++) acc[i] = 0.f;
    for (int r = blockIdx.x; r < N_; r += gridDim.x) {
        if (t < 100) ssh[t] = s[(size_t)r * 100 + t];
        if (t < 128) hsh[t] = hf[(size_t)r * 128 + t];
        __syncthreads();
        float hv = hsh[col];
#pragma unroll
        for (int i = 0; i < 50; i++) acc[i] += ssh[2 * i + half] * hv;
        __syncthreads();
    }
#pragma unroll
    for (int i = 0; i < 50; i++) atomicAdd(&hc[(2 * i + half) * 128 + col], acc[i]);
}

// ---------------- h = mask(0.5*h_fine + 0.5*(s@h_coarse)) ----------------
__global__ __launch_bounds__(128) void k_combine(const float* __restrict__ s,
                                                 const float* __restrict__ hc,
                                                 const float* __restrict__ hfine,
                                                 float* __restrict__ hout) {
    __shared__ float ssh[100];
    int n = blockIdx.x, t = threadIdx.x;
    if (t < 100) ssh[t] = s[(size_t)n * 100 + t];
    __syncthreads();
    float acc = 0.f;
    for (int a = 0; a < 100; a++) acc += ssh[a] * hc[a * 128 + t];
    float v = 0.5f * hfine[(size_t)n * 128 + t] + 0.5f * acc;
    if (isinf(v)) v = 1e9f;
    hout[(size_t)n * 128 + t] = v;
}

// ---------------- edge MLP readout (wave per edge) ----------------
__global__ __launch_bounds__(256, 1) void k_edge_mlp(const float* __restrict__ P,
                                                     const float* __restrict__ Q,
                                                     const int* __restrict__ src,
                                                     const int* __restrict__ dst,
                                                     const float* __restrict__ bm1,
                                                     const float* __restrict__ Wm2,
                                                     const float* __restrict__ bm2,
                                                     const float* __restrict__ Wm3,
                                                     const float* __restrict__ bm3,
                                                     float* __restrict__ zout) {
    int lane = threadIdx.x & 63;
    int gw = (blockIdx.x * blockDim.x + threadIdx.x) >> 6;
    int nw = (gridDim.x * blockDim.x) >> 6;
    float w[128];
#pragma unroll
    for (int j = 0; j < 128; j++) w[j] = Wm2[j * 64 + lane];
    float w3a = Wm3[lane * 2 + 0], w3b = Wm3[lane * 2 + 1];
    float bm2v = bm2[lane];
    float b30 = bm3[0], b31 = bm3[1];
    float2 bb = *(const float2*)(bm1 + 2 * lane);
    for (int e = gw; e < E_; e += nw) {
        int sI = src[e], dI = dst[e];
        float2 p = *(const float2*)(P + (size_t)sI * 128 + 2 * lane);
        float2 q = *(const float2*)(Q + (size_t)dI * 128 + 2 * lane);
        float t0 = fmaxf(p.x + q.x + bb.x, 0.f);
        float t1 = fmaxf(p.y + q.y + bb.y, 0.f);
        float u = bm2v;
#pragma unroll
        for (int j = 0; j < 64; j++) {
            u += rdlane(t0, j) * w[2 * j];
            u += rdlane(t1, j) * w[2 * j + 1];
        }
        u = fmaxf(u, 0.f);
        float z0 = u * w3a, z1 = u * w3b;
#pragma unroll
        for (int off = 1; off < 64; off <<= 1) {
            z0 += __shfl_xor(z0, off);
            z1 += __shfl_xor(z1, off);
        }
        if (lane == 0) {
            z0 += b30; z1 += b31;
            if (isinf(z0)) z0 = 1e9f;
            if (isinf(z1)) z1 = 1e9f;
            *(float2*)(zout + (size_t)e * 2) = make_float2(z0, z1);
        }
    }
}

extern "C" void kernel_launch(void* const* d_in, const int* in_sizes, int n_in,
                              void* d_out, int out_size, void* d_ws, size_t ws_size,
                              hipStream_t stream) {
    const float* h_in  = (const float*)d_in[0];
    const int*   src   = (const int*)d_in[2];
    const int*   dst   = (const int*)d_in[3];
    const float* W_emb = (const float*)d_in[4];
    const float* b_emb = (const float*)d_in[5];
    const float* Wg    = (const float*)d_in[6];
    const float* alg   = (const float*)d_in[7];
    const float* arg_  = (const float*)d_in[8];
    const float* bg    = (const float*)d_in[9];
    const float* gam   = (const float*)d_in[10];
    const float* bet   = (const float*)d_in[11];
    const float* W3    = (const float*)d_in[12];
    const float* al3   = (const float*)d_in[13];
    const float* ar3   = (const float*)d_in[14];
    const float* b3    = (const float*)d_in[15];
    const float* gam3  = (const float*)d_in[16];
    const float* bet3  = (const float*)d_in[17];
    const float* Wa    = (const float*)d_in[18];
    const float* ba    = (const float*)d_in[19];
    const float* Wm1   = (const float*)d_in[20];
    const float* bm1   = (const float*)d_in[21];
    const float* Wm2   = (const float*)d_in[22];
    const float* bm2   = (const float*)d_in[23];
    const float* Wm3   = (const float*)d_in[24];
    const float* bm3   = (const float*)d_in[25];

    float* zout = (float*)d_out;
    float* sout = zout + (size_t)E_ * 2;

    float* ws = (float*)d_ws;
    size_t o = 0;
    float* h_cur = ws + o; o += (size_t)N_ * 128;
    float* xbuf  = ws + o; o += (size_t)N_ * 128;
    float* featb = ws + o; o += (size_t)N_ * 128;
    float* el    = ws + o; o += (size_t)N_ * 8;
    float* er    = ws + o; o += (size_t)N_ * 8;
    float* colsum = ws + o; o += 128;
    float* colsq  = ws + o; o += 128;
    float* hc     = ws + o; o += 100 * 128;
    int* counts = (int*)(ws + o); o += N_;
    int* rowptr = (int*)(ws + o); o += N_ + 4;
    int* cursor = (int*)(ws + o); o += N_;
    int* srcv   = (int*)(ws + o); o += E_;

    // ---- CSR build ----
    hipMemsetAsync(counts, 0, N_ * sizeof(int), stream);
    k_count<<<1024, 256, 0, stream>>>(dst, counts);
    k_scan<<<1, 1024, 0, stream>>>(counts, rowptr, cursor);
    k_fill<<<1024, 256, 0, stream>>>(src, dst, cursor, srcv);

    // ---- embedding ----
    k_gemm128<<<N_ / 8, 256, 0, stream>>>(h_in, W_emb, b_emb, h_cur);

    // ---- layer 0 (H=8) ----
    k_gemm128<<<N_ / 8, 256, 0, stream>>>(h_cur, Wg + 0 * 16384, nullptr, featb);
    k_elr<8><<<N_ / 4, 256, 0, stream>>>(featb, alg + 0 * 128, arg_ + 0 * 128, el, er);
    k_gat_agg<8><<<N_ / 4, 256, 0, stream>>>(featb, el, er, rowptr, srcv, bg + 0 * 128, xbuf);
    hipMemsetAsync(colsum, 0, 256 * sizeof(float), stream);
    k_bn_stats<<<512, 256, 0, stream>>>(xbuf, colsum, colsq);
    k_bn_apply<<<(N_ * 128) / 256, 256, 0, stream>>>(xbuf, h_cur, colsum, colsq,
                                                     gam + 0 * 128, bet + 0 * 128, h_cur, 1);

    // ---- layer 1 (biGAT, H=8) ----
    k_s<<<N_, 128, 0, stream>>>(h_cur, Wa, ba, sout);  // s from h_in
    k_gemm128<<<N_ / 8, 256, 0, stream>>>(h_cur, Wg + 1 * 16384, nullptr, featb);
    k_elr<8><<<N_ / 4, 256, 0, stream>>>(featb, alg + 1 * 128, arg_ + 1 * 128, el, er);
    k_gat_agg<8><<<N_ / 4, 256, 0, stream>>>(featb, el, er, rowptr, srcv, bg + 1 * 128, xbuf);
    hipMemsetAsync(colsum, 0, 256 * sizeof(float), stream);
    k_bn_stats<<<512, 256, 0, stream>>>(xbuf, colsum, colsq);
    // h_fine into xbuf (in-place elementwise), NOT masked
    k_bn_apply<<<(N_ * 128) / 256, 256, 0, stream>>>(xbuf, h_cur, colsum, colsq,
                                                     gam + 1 * 128, bet + 1 * 128, xbuf, 0);
    hipMemsetAsync(hc, 0, 100 * 128 * sizeof(float), stream);
    k_coarse<<<256, 256, 0, stream>>>(sout, xbuf, hc);
    k_combine<<<N_, 128, 0, stream>>>(sout, hc, xbuf, h_cur);

    // ---- layer 2 (H=8) ----
    k_gemm128<<<N_ / 8, 256, 0, stream>>>(h_cur, Wg + 2 * 16384, nullptr, featb);
    k_elr<8><<<N_ / 4, 256, 0, stream>>>(featb, alg + 2 * 128, arg_ + 2 * 128, el, er);
    k_gat_agg<8><<<N_ / 4, 256, 0, stream>>>(featb, el, er, rowptr, srcv, bg + 2 * 128, xbuf);
    hipMemsetAsync(colsum, 0, 256 * sizeof(float), stream);
    k_bn_stats<<<512, 256, 0, stream>>>(xbuf, colsum, colsq);
    k_bn_apply<<<(N_ * 128) / 256, 256, 0, stream>>>(xbuf, h_cur, colsum, colsq,
                                                     gam + 2 * 128, bet + 2 * 128, h_cur, 1);

    // ---- layer 3 (H=1) ----
    k_gemm128<<<N_ / 8, 256, 0, stream>>>(h_cur, W3, nullptr, featb);
    k_elr<1><<<N_ / 4, 256, 0, stream>>>(featb, al3, ar3, el, er);
    k_gat_agg<1><<<N_ / 4, 256, 0, stream>>>(featb, el, er, rowptr, srcv, b3, xbuf);
    hipMemsetAsync(colsum, 0, 256 * sizeof(float), stream);
    k_bn_stats<<<512, 256, 0, stream>>>(xbuf, colsum, colsq);
    k_bn_apply<<<(N_ * 128) / 256, 256, 0, stream>>>(xbuf, h_cur, colsum, colsq,
                                                     gam3, bet3, h_cur, 1);

    // ---- edge MLP readout: P = h@Wm1[:128], Q = h@Wm1[128:] ----
    k_gemm128<<<N_ / 8, 256, 0, stream>>>(h_cur, Wm1, nullptr, featb);          // P
    k_gemm128<<<N_ / 8, 256, 0, stream>>>(h_cur, Wm1 + 128 * 128, nullptr, xbuf); // Q
    k_edge_mlp<<<1024, 256, 0, stream>>>(featb, xbuf, src, dst, bm1, Wm2, bm2, Wm3, bm3, zout);
}

// Round 3
// 1441.734 us; speedup vs baseline: 1.2390x; 1.2390x over previous
//
#include <hip/hip_runtime.h>
#include <hip/hip_bf16.h>
#include <math.h>

#define N_ 40000
#define E_ 640000

typedef short bf16x8 __attribute__((ext_vector_type(8)));
typedef float floatx4 __attribute__((ext_vector_type(4)));

__device__ __forceinline__ short f2bf(float f) {
    __hip_bfloat16 h = __float2bfloat16(f);
    return *reinterpret_cast<short*>(&h);
}

// ---------------- CSR build ----------------
__global__ void k_count(const int* __restrict__ dst, int* __restrict__ counts) {
    for (int e = blockIdx.x * blockDim.x + threadIdx.x; e < E_; e += gridDim.x * blockDim.x)
        atomicAdd(&counts[dst[e]], 1);
}

__global__ void k_scan(const int* __restrict__ counts, int* __restrict__ rowptr,
                       int* __restrict__ cursor) {
    __shared__ int buf[1024];
    int t = threadIdx.x;
    int carry = 0;
    for (int base = 0; base < N_; base += 1024) {
        int i = base + t;
        int v = (i < N_) ? counts[i] : 0;
        buf[t] = v;
        __syncthreads();
        for (int off = 1; off < 1024; off <<= 1) {
            int add = (t >= off) ? buf[t - off] : 0;
            __syncthreads();
            buf[t] += add;
            __syncthreads();
        }
        int incl = buf[t];
        int excl = incl - v;
        if (i < N_) { rowptr[i] = carry + excl; cursor[i] = carry + excl; }
        int total = buf[1023];
        __syncthreads();
        carry += total;
    }
    if (t == 0) rowptr[N_] = carry;
}

__global__ void k_fill(const int* __restrict__ src, const int* __restrict__ dst,
                       int* __restrict__ cursor, int* __restrict__ srcv) {
    for (int e = blockIdx.x * blockDim.x + threadIdx.x; e < E_; e += gridDim.x * blockDim.x) {
        int d = dst[e];
        int pos = atomicAdd(&cursor[d], 1);
        srcv[pos] = src[e];
    }
}

// ---------------- GEMM [N,128] x [128,128] (+bias) ----------------
__global__ __launch_bounds__(256) void k_gemm128(const float* __restrict__ A,
                                                 const float* __restrict__ W,
                                                 const float* __restrict__ bias,
                                                 float* __restrict__ C) {
    __shared__ float As[8 * 128];
    int t = threadIdx.x;
    int r0 = blockIdx.x * 8;
    *(float4*)(As + t * 4) = *(const float4*)(A + (size_t)r0 * 128 + t * 4);
    __syncthreads();
    int c = t & 127, g = t >> 7;
    float a0 = 0.f, a1 = 0.f, a2 = 0.f, a3 = 0.f;
#pragma unroll 4
    for (int k = 0; k < 128; k++) {
        float wv = W[k * 128 + c];
        a0 += As[(g * 4 + 0) * 128 + k] * wv;
        a1 += As[(g * 4 + 1) * 128 + k] * wv;
        a2 += As[(g * 4 + 2) * 128 + k] * wv;
        a3 += As[(g * 4 + 3) * 128 + k] * wv;
    }
    float bv = bias ? bias[c] : 0.f;
    C[(size_t)(r0 + g * 4 + 0) * 128 + c] = a0 + bv;
    C[(size_t)(r0 + g * 4 + 1) * 128 + c] = a1 + bv;
    C[(size_t)(r0 + g * 4 + 2) * 128 + c] = a2 + bv;
    C[(size_t)(r0 + g * 4 + 3) * 128 + c] = a3 + bv;
}

// ---------------- per-node attention logits el/er ----------------
template <int H>
__global__ __launch_bounds__(256) void k_elr(const float* __restrict__ feat,
                                             const float* __restrict__ al,
                                             const float* __restrict__ ar,
                                             float* __restrict__ el, float* __restrict__ er) {
    int lane = threadIdx.x & 63;
    int n = blockIdx.x * 4 + (threadIdx.x >> 6);
    if (n >= N_) return;
    float2 f = *(const float2*)(feat + (size_t)n * 128 + 2 * lane);
    float2 a = *(const float2*)(al + 2 * lane);
    float2 b = *(const float2*)(ar + 2 * lane);
    float pl = f.x * a.x + f.y * a.y;
    float pr = f.x * b.x + f.y * b.y;
    constexpr int G = 64 / H;
#pragma unroll
    for (int off = 1; off < G; off <<= 1) {
        pl += __shfl_xor(pl, off);
        pr += __shfl_xor(pr, off);
    }
    if ((lane & (G - 1)) == 0) {
        int hh = lane / G;
        el[(size_t)n * H + hh] = pl;
        er[(size_t)n * H + hh] = pr;
    }
}

// ---------------- GAT edge-softmax + aggregate (wave per dst node) ----------------
template <int H>
__global__ __launch_bounds__(256) void k_gat_agg(const float* __restrict__ feat,
                                                 const float* __restrict__ el,
                                                 const float* __restrict__ er,
                                                 const int* __restrict__ rowptr,
                                                 const int* __restrict__ srcv,
                                                 const float* __restrict__ bias,
                                                 float* __restrict__ xout) {
    int lane = threadIdx.x & 63;
    int n = blockIdx.x * 4 + (threadIdx.x >> 6);
    if (n >= N_) return;
    int beg = rowptr[n], end = rowptr[n + 1];
    int f0 = 2 * lane;
    if (beg == end) {
        *(float2*)(xout + (size_t)n * 128 + f0) = *(const float2*)(bias + f0);
        return;
    }
    constexpr int LH = (H == 8) ? 3 : 0;
    int h = lane & (H - 1);
    float ern = er[(size_t)n * H + h];
    float m = -INFINITY, ss = 0.f;
    for (int e = beg + (lane >> LH); e < end; e += (64 >> LH)) {
        int sI = srcv[e];
        float x = el[(size_t)sI * H + h] + ern;
        float lr = x > 0.f ? x : 0.2f * x;
        if (lr > m) { ss = ss * __expf(m - lr) + 1.f; m = lr; }
        else ss += __expf(lr - m);
    }
#pragma unroll
    for (int off = H; off < 64; off <<= 1) {
        float om = __shfl_xor(m, off);
        float os = __shfl_xor(ss, off);
        float nm = fmaxf(m, om);
        float p1 = (m == -INFINITY) ? 0.f : ss * __expf(m - nm);
        float p2 = (om == -INFINITY) ? 0.f : os * __expf(om - nm);
        m = nm; ss = p1 + p2;
    }
    int hf = (lane * H) >> 6;
    float mh = __shfl(m, hf);
    float dh = __shfl(ss, hf);
    float inv_d = 1.f / dh;
    float ernf = er[(size_t)n * H + hf];
    float accx = 0.f, accy = 0.f;
    for (int e = beg; e < end; ++e) {
        int sI = srcv[e];
        float x = el[(size_t)sI * H + hf] + ernf;
        float lr = x > 0.f ? x : 0.2f * x;
        float a = __expf(lr - mh) * inv_d;
        float2 f2 = *(const float2*)(feat + (size_t)sI * 128 + f0);
        accx += a * f2.x;
        accy += a * f2.y;
    }
    float2 b2 = *(const float2*)(bias + f0);
    *(float2*)(xout + (size_t)n * 128 + f0) = make_float2(accx + b2.x, accy + b2.y);
}

// ---------------- BN stats ----------------
__global__ __launch_bounds__(256) void k_bn_stats(const float* __restrict__ x,
                                                  float* __restrict__ sum,
                                                  float* __restrict__ sumsq) {
    __shared__ float ls[256], lq[256];
    int t = threadIdx.x;
    int col = t & 127, half = t >> 7;
    float s = 0.f, q = 0.f;
    for (int r = blockIdx.x * 2 + half; r < N_; r += gridDim.x * 2) {
        float v = x[(size_t)r * 128 + col];
        s += v; q += v * v;
    }
    ls[t] = s; lq[t] = q;
    __syncthreads();
    if (t < 128) {
        atomicAdd(&sum[col], ls[t] + ls[t + 128]);
        atomicAdd(&sumsq[col], lq[t] + lq[t + 128]);
    }
}

// ---------------- BN apply + ELU + residual (+mask) ----------------
__global__ __launch_bounds__(256) void k_bn_apply(const float* __restrict__ x,
                                                  const float* __restrict__ hprev,
                                                  const float* __restrict__ sum,
                                                  const float* __restrict__ sumsq,
                                                  const float* __restrict__ g,
                                                  const float* __restrict__ b,
                                                  float* __restrict__ out, int do_mask) {
    int i = blockIdx.x * blockDim.x + threadIdx.x;
    if (i >= N_ * 128) return;
    int c = i & 127;
    const float invN = 1.f / (float)N_;
    float mu = sum[c] * invN;
    float var = sumsq[c] * invN - mu * mu;
    float inv = rsqrtf(var + 1e-5f);
    float y = g[c] * (x[i] - mu) * inv + b[c];
    y = y > 0.f ? y : (__expf(y) - 1.f);
    float hv = hprev[i] + y;
    if (do_mask && isinf(hv)) hv = 1e9f;
    out[i] = hv;
}

// ---------------- assignment softmax s = softmax(h@Wa+ba) ----------------
__global__ __launch_bounds__(128) void k_s(const float* __restrict__ h,
                                           const float* __restrict__ Wa,
                                           const float* __restrict__ ba,
                                           float* __restrict__ s) {
    __shared__ float hrow[128];
    __shared__ float red[128];
    int n = blockIdx.x, t = threadIdx.x;
    hrow[t] = h[(size_t)n * 128 + t];
    __syncthreads();
    float acc = 0.f;
    if (t < 100) {
        acc = ba[t];
        for (int k = 0; k < 128; k++) acc += hrow[k] * Wa[k * 100 + t];
    }
    red[t] = (t < 100) ? acc : -INFINITY;
    __syncthreads();
    for (int off = 64; off > 0; off >>= 1) {
        if (t < off) red[t] = fmaxf(red[t], red[t + off]);
        __syncthreads();
    }
    float mx = red[0];
    __syncthreads();
    float ex = (t < 100) ? __expf(acc - mx) : 0.f;
    red[t] = ex;
    __syncthreads();
    for (int off = 64; off > 0; off >>= 1) {
        if (t < off) red[t] += red[t + off];
        __syncthreads();
    }
    float den = red[0];
    if (t < 100) s[(size_t)n * 100 + t] = ex / den;
}

// ---------------- h_coarse = s^T @ h_fine ----------------
__global__ __launch_bounds__(256) void k_coarse(const float* __restrict__ s,
                                                const float* __restrict__ hf,
                                                float* __restrict__ hc) {
    __shared__ float ssh[100];
    __shared__ float hsh[128];
    int t = threadIdx.x;
    int col = t & 127, half = t >> 7;
    float acc[50];
#pragma unroll
    for (int i = 0; i < 50; i++) acc[i] = 0.f;
    for (int r = blockIdx.x; r < N_; r += gridDim.x) {
        if (t < 100) ssh[t] = s[(size_t)r * 100 + t];
        if (t < 128) hsh[t] = hf[(size_t)r * 128 + t];
        __syncthreads();
        float hv = hsh[col];
#pragma unroll
        for (int i = 0; i < 50; i++) acc[i] += ssh[2 * i + half] * hv;
        __syncthreads();
    }
#pragma unroll
    for (int i = 0; i < 50; i++) atomicAdd(&hc[(2 * i + half) * 128 + col], acc[i]);
}

// ---------------- h = mask(0.5*h_fine + 0.5*(s@h_coarse)) ----------------
__global__ __launch_bounds__(128) void k_combine(const float* __restrict__ s,
                                                 const float* __restrict__ hc,
                                                 const float* __restrict__ hfine,
                                                 float* __restrict__ hout) {
    __shared__ float ssh[100];
    int n = blockIdx.x, t = threadIdx.x;
    if (t < 100) ssh[t] = s[(size_t)n * 100 + t];
    __syncthreads();
    float acc = 0.f;
    for (int a = 0; a < 100; a++) acc += ssh[a] * hc[a * 128 + t];
    float v = 0.5f * hfine[(size_t)n * 128 + t] + 0.5f * acc;
    if (isinf(v)) v = 1e9f;
    hout[(size_t)n * 128 + t] = v;
}

// ---------------- prep: Wm2 [128][64] fp32 -> Wm2T bf16 [64][128] ----------------
__global__ __launch_bounds__(256) void k_prep_w(const float* __restrict__ Wm2,
                                                short* __restrict__ Wm2T) {
    int i = blockIdx.x * blockDim.x + threadIdx.x;  // 8192 total
    if (i >= 64 * 128) return;
    int n = i & 63, k = i >> 6;
    Wm2T[n * 128 + k] = f2bf(Wm2[k * 64 + n]);
}

// ---------------- edge MLP readout via MFMA ----------------
// block = 256 threads (4 waves), 64 edges/block.
// A = relu(P[src]+Q[dst]+bm1) [64 x 128] bf16 in LDS (row pad 136)
// B = Wm2^T [64 x 128] bf16 in LDS ([n][k], row pad 136)
// wave w computes rows 16w..16w+15, N=64 via 4x4 mfma_f32_16x16x32_bf16,
// then folds relu(u)@Wm3 + bm3 in-register (16-lane shuffle reduce).
__global__ __launch_bounds__(256) void k_edge_mlp(const float* __restrict__ P,
                                                  const float* __restrict__ Q,
                                                  const int* __restrict__ src,
                                                  const int* __restrict__ dst,
                                                  const float* __restrict__ bm1,
                                                  const short* __restrict__ Wm2T,
                                                  const float* __restrict__ bm2,
                                                  const float* __restrict__ Wm3,
                                                  const float* __restrict__ bm3,
                                                  float* __restrict__ zout) {
    __shared__ short sA[64 * 136];
    __shared__ short sB[64 * 136];
    __shared__ int sIdx[128];

    int t = threadIdx.x;
    int e0 = blockIdx.x * 64;

    // stage edge indices: sIdx[0..63]=src, sIdx[64..127]=dst
    if (t < 64) sIdx[t] = src[e0 + t];
    else if (t < 128) sIdx[t] = dst[e0 + t - 64];
    // stage B = Wm2^T bf16
    {
        int n = t >> 2, k0 = (t & 3) * 32;
#pragma unroll
        for (int j = 0; j < 4; j++) {
            bf16x8 v = *(const bf16x8*)(Wm2T + n * 128 + k0 + 8 * j);
            *(bf16x8*)(sB + n * 136 + k0 + 8 * j) = v;
        }
    }
    __syncthreads();

    // stage A = relu(P[s]+Q[d]+bm1), bf16
    {
        int ei = t >> 2, k0 = (t & 3) * 32;
        int s = sIdx[ei], d = sIdx[64 + ei];
        const float* prow = P + (size_t)s * 128 + k0;
        const float* qrow = Q + (size_t)d * 128 + k0;
        const float* brow = bm1 + k0;
#pragma unroll
        for (int j = 0; j < 4; j++) {
            float4 p0 = *(const float4*)(prow + 8 * j);
            float4 p1 = *(const float4*)(prow + 8 * j + 4);
            float4 q0 = *(const float4*)(qrow + 8 * j);
            float4 q1 = *(const float4*)(qrow + 8 * j + 4);
            float4 b0 = *(const float4*)(brow + 8 * j);
            float4 b1 = *(const float4*)(brow + 8 * j + 4);
            bf16x8 v;
            v[0] = f2bf(fmaxf(p0.x + q0.x + b0.x, 0.f));
            v[1] = f2bf(fmaxf(p0.y + q0.y + b0.y, 0.f));
            v[2] = f2bf(fmaxf(p0.z + q0.z + b0.z, 0.f));
            v[3] = f2bf(fmaxf(p0.w + q0.w + b0.w, 0.f));
            v[4] = f2bf(fmaxf(p1.x + q1.x + b1.x, 0.f));
            v[5] = f2bf(fmaxf(p1.y + q1.y + b1.y, 0.f));
            v[6] = f2bf(fmaxf(p1.z + q1.z + b1.z, 0.f));
            v[7] = f2bf(fmaxf(p1.w + q1.w + b1.w, 0.f));
            *(bf16x8*)(sA + ei * 136 + k0 + 8 * j) = v;
        }
    }
    __syncthreads();

    int wv = t >> 6, lane = t & 63;
    int m0 = wv * 16;
    int lm = lane & 15, quad = lane >> 4;

    bf16x8 aF[4];
#pragma unroll
    for (int kt = 0; kt < 4; kt++)
        aF[kt] = *(const bf16x8*)(sA + (m0 + lm) * 136 + kt * 32 + quad * 8);

    floatx4 acc[4];
#pragma unroll
    for (int nt = 0; nt < 4; nt++) {
        acc[nt] = (floatx4){0.f, 0.f, 0.f, 0.f};
#pragma unroll
        for (int kt = 0; kt < 4; kt++) {
            bf16x8 bF = *(const bf16x8*)(sB + (nt * 16 + lm) * 136 + kt * 32 + quad * 8);
            acc[nt] = __builtin_amdgcn_mfma_f32_16x16x32_bf16(aF[kt], bF, acc[nt], 0, 0, 0);
        }
    }

    // epilogue: u = relu(acc + bm2[n]); z = u @ Wm3 + bm3
    float pz0[4] = {0.f, 0.f, 0.f, 0.f};
    float pz1[4] = {0.f, 0.f, 0.f, 0.f};
#pragma unroll
    for (int nt = 0; nt < 4; nt++) {
        int n = nt * 16 + lm;
        float bv = bm2[n];
        float w30 = Wm3[n * 2 + 0], w31 = Wm3[n * 2 + 1];
#pragma unroll
        for (int r = 0; r < 4; r++) {
            float u = fmaxf(acc[nt][r] + bv, 0.f);
            pz0[r] += u * w30;
            pz1[r] += u * w31;
        }
    }
#pragma unroll
    for (int off = 1; off < 16; off <<= 1) {
#pragma unroll
        for (int r = 0; r < 4; r++) {
            pz0[r] += __shfl_xor(pz0[r], off);
            pz1[r] += __shfl_xor(pz1[r], off);
        }
    }
    if (lm < 4) {
        int r = lm;
        int e = e0 + m0 + quad * 4 + r;
        float z0 = pz0[r] + bm3[0];
        float z1 = pz1[r] + bm3[1];
        if (isinf(z0)) z0 = 1e9f;
        if (isinf(z1)) z1 = 1e9f;
        *(float2*)(zout + (size_t)e * 2) = make_float2(z0, z1);
    }
}

extern "C" void kernel_launch(void* const* d_in, const int* in_sizes, int n_in,
                              void* d_out, int out_size, void* d_ws, size_t ws_size,
                              hipStream_t stream) {
    const float* h_in  = (const float*)d_in[0];
    const int*   src   = (const int*)d_in[2];
    const int*   dst   = (const int*)d_in[3];
    const float* W_emb = (const float*)d_in[4];
    const float* b_emb = (const float*)d_in[5];
    const float* Wg    = (const float*)d_in[6];
    const float* alg   = (const float*)d_in[7];
    const float* arg_  = (const float*)d_in[8];
    const float* bg    = (const float*)d_in[9];
    const float* gam   = (const float*)d_in[10];
    const float* bet   = (const float*)d_in[11];
    const float* W3    = (const float*)d_in[12];
    const float* al3   = (const float*)d_in[13];
    const float* ar3   = (const float*)d_in[14];
    const float* b3    = (const float*)d_in[15];
    const float* gam3  = (const float*)d_in[16];
    const float* bet3  = (const float*)d_in[17];
    const float* Wa    = (const float*)d_in[18];
    const float* ba    = (const float*)d_in[19];
    const float* Wm1   = (const float*)d_in[20];
    const float* bm1   = (const float*)d_in[21];
    const float* Wm2   = (const float*)d_in[22];
    const float* bm2   = (const float*)d_in[23];
    const float* Wm3   = (const float*)d_in[24];
    const float* bm3   = (const float*)d_in[25];

    float* zout = (float*)d_out;
    float* sout = zout + (size_t)E_ * 2;

    float* ws = (float*)d_ws;
    size_t o = 0;
    float* h_cur = ws + o; o += (size_t)N_ * 128;
    float* xbuf  = ws + o; o += (size_t)N_ * 128;
    float* featb = ws + o; o += (size_t)N_ * 128;
    float* el    = ws + o; o += (size_t)N_ * 8;
    float* er    = ws + o; o += (size_t)N_ * 8;
    float* colsum = ws + o; o += 128;
    float* colsq  = ws + o; o += 128;
    float* hc     = ws + o; o += 100 * 128;
    short* Wm2T = (short*)(ws + o); o += (64 * 128) / 2;
    int* counts = (int*)(ws + o); o += N_;
    int* rowptr = (int*)(ws + o); o += N_ + 4;
    int* cursor = (int*)(ws + o); o += N_;
    int* srcv   = (int*)(ws + o); o += E_;

    // ---- CSR build ----
    hipMemsetAsync(counts, 0, N_ * sizeof(int), stream);
    k_count<<<1024, 256, 0, stream>>>(dst, counts);
    k_scan<<<1, 1024, 0, stream>>>(counts, rowptr, cursor);
    k_fill<<<1024, 256, 0, stream>>>(src, dst, cursor, srcv);
    k_prep_w<<<32, 256, 0, stream>>>(Wm2, Wm2T);

    // ---- embedding ----
    k_gemm128<<<N_ / 8, 256, 0, stream>>>(h_in, W_emb, b_emb, h_cur);

    // ---- layer 0 (H=8) ----
    k_gemm128<<<N_ / 8, 256, 0, stream>>>(h_cur, Wg + 0 * 16384, nullptr, featb);
    k_elr<8><<<N_ / 4, 256, 0, stream>>>(featb, alg + 0 * 128, arg_ + 0 * 128, el, er);
    k_gat_agg<8><<<N_ / 4, 256, 0, stream>>>(featb, el, er, rowptr, srcv, bg + 0 * 128, xbuf);
    hipMemsetAsync(colsum, 0, 256 * sizeof(float), stream);
    k_bn_stats<<<512, 256, 0, stream>>>(xbuf, colsum, colsq);
    k_bn_apply<<<(N_ * 128) / 256, 256, 0, stream>>>(xbuf, h_cur, colsum, colsq,
                                                     gam + 0 * 128, bet + 0 * 128, h_cur, 1);

    // ---- layer 1 (biGAT, H=8) ----
    k_s<<<N_, 128, 0, stream>>>(h_cur, Wa, ba, sout);
    k_gemm128<<<N_ / 8, 256, 0, stream>>>(h_cur, Wg + 1 * 16384, nullptr, featb);
    k_elr<8><<<N_ / 4, 256, 0, stream>>>(featb, alg + 1 * 128, arg_ + 1 * 128, el, er);
    k_gat_agg<8><<<N_ / 4, 256, 0, stream>>>(featb, el, er, rowptr, srcv, bg + 1 * 128, xbuf);
    hipMemsetAsync(colsum, 0, 256 * sizeof(float), stream);
    k_bn_stats<<<512, 256, 0, stream>>>(xbuf, colsum, colsq);
    k_bn_apply<<<(N_ * 128) / 256, 256, 0, stream>>>(xbuf, h_cur, colsum, colsq,
                                                     gam + 1 * 128, bet + 1 * 128, xbuf, 0);
    hipMemsetAsync(hc, 0, 100 * 128 * sizeof(float), stream);
    k_coarse<<<256, 256, 0, stream>>>(sout, xbuf, hc);
    k_combine<<<N_, 128, 0, stream>>>(sout, hc, xbuf, h_cur);

    // ---- layer 2 (H=8) ----
    k_gemm128<<<N_ / 8, 256, 0, stream>>>(h_cur, Wg + 2 * 16384, nullptr, featb);
    k_elr<8><<<N_ / 4, 256, 0, stream>>>(featb, alg + 2 * 128, arg_ + 2 * 128, el, er);
    k_gat_agg<8><<<N_ / 4, 256, 0, stream>>>(featb, el, er, rowptr, srcv, bg + 2 * 128, xbuf);
    hipMemsetAsync(colsum, 0, 256 * sizeof(float), stream);
    k_bn_stats<<<512, 256, 0, stream>>>(xbuf, colsum, colsq);
    k_bn_apply<<<(N_ * 128) / 256, 256, 0, stream>>>(xbuf, h_cur, colsum, colsq,
                                                     gam + 2 * 128, bet + 2 * 128, h_cur, 1);

    // ---- layer 3 (H=1) ----
    k_gemm128<<<N_ / 8, 256, 0, stream>>>(h_cur, W3, nullptr, featb);
    k_elr<1><<<N_ / 4, 256, 0, stream>>>(featb, al3, ar3, el, er);
    k_gat_agg<1><<<N_ / 4, 256, 0, stream>>>(featb, el, er, rowptr, srcv, b3, xbuf);
    hipMemsetAsync(colsum, 0, 256 * sizeof(float), stream);
    k_bn_stats<<<512, 256, 0, stream>>>(xbuf, colsum, colsq);
    k_bn_apply<<<(N_ * 128) / 256, 256, 0, stream>>>(xbuf, h_cur, colsum, colsq,
                                                     gam3, bet3, h_cur, 1);

    // ---- edge MLP readout: P = h@Wm1[:128], Q = h@Wm1[128:] ----
    k_gemm128<<<N_ / 8, 256, 0, stream>>>(h_cur, Wm1, nullptr, featb);            // P
    k_gemm128<<<N_ / 8, 256, 0, stream>>>(h_cur, Wm1 + 128 * 128, nullptr, xbuf); // Q
    k_edge_mlp<<<E_ / 64, 256, 0, stream>>>(featb, xbuf, src, dst, bm1, Wm2T, bm2, Wm3, bm3, zout);
}